// Round 12
// baseline (206.593 us; speedup 1.0000x reference)
//
#include <hip/hip_runtime.h>
#include <hip/hip_bf16.h>

typedef float f32x4 __attribute__((ext_vector_type(4)));
typedef short s16x8 __attribute__((ext_vector_type(8)));
typedef unsigned short u16x4 __attribute__((ext_vector_type(4)));
typedef unsigned short u16x8 __attribute__((ext_vector_type(8)));

#define MFMA16(a,b,c) __builtin_amdgcn_mfma_f32_16x16x32_bf16(a,b,c,0,0,0)

#define NTOK 3136
#define NKV  784
#define NKVP 800
#define CD   256
#define NH   8
#define HD   32
#define PEW  111
#define LOG2E 1.4426950408889634f
#define SC2  (0.17677669529663687f * 1.4426950408889634f)

static __device__ __forceinline__ unsigned short f2b(float f){
  unsigned int u = __float_as_uint(f);
  return (unsigned short)((u + 0x7fffu + ((u>>16)&1u)) >> 16);
}
static __device__ __forceinline__ float b2f(unsigned short u){
  return __uint_as_float(((unsigned int)u)<<16);
}
static __device__ __forceinline__ void gload16(const unsigned short* g, unsigned short* l){
  __builtin_amdgcn_global_load_lds(
      (const __attribute__((address_space(1))) unsigned int*)g,
      (__attribute__((address_space(3))) unsigned int*)l, 16, 0, 0);
}
// fast bf16 pack of 8 positive floats (round-half-up)
static __device__ __forceinline__ s16x8 pack8(const float* p){
  union { uint4 u; s16x8 s; } w;
  unsigned int a0=__float_as_uint(p[0])+0x8000u, a1=__float_as_uint(p[1])+0x8000u;
  unsigned int a2=__float_as_uint(p[2])+0x8000u, a3=__float_as_uint(p[3])+0x8000u;
  unsigned int a4=__float_as_uint(p[4])+0x8000u, a5=__float_as_uint(p[5])+0x8000u;
  unsigned int a6=__float_as_uint(p[6])+0x8000u, a7=__float_as_uint(p[7])+0x8000u;
  w.u.x = (a0>>16) | (a1 & 0xFFFF0000u);
  w.u.y = (a2>>16) | (a3 & 0xFFFF0000u);
  w.u.z = (a4>>16) | (a5 & 0xFFFF0000u);
  w.u.w = (a6>>16) | (a7 & 0xFFFF0000u);
  return w.s;
}

// ---- fused prep (unchanged from round 11)
__global__ __launch_bounds__(256) void k_prep(
      const float* __restrict__ Wq, const float* __restrict__ Wkv,
      const float* __restrict__ pw, const float* __restrict__ srw,
      const float* __restrict__ pos, const float* __restrict__ x,
      unsigned short* __restrict__ WqT, unsigned short* __restrict__ WkvT,
      unsigned short* __restrict__ pwT, unsigned short* __restrict__ srwb2,
      unsigned short* __restrict__ bias2, unsigned short* __restrict__ xbf,
      unsigned short* __restrict__ kb, unsigned short* __restrict__ vT){
  __shared__ float tile[64][65];
  const int blk = blockIdx.x, t = threadIdx.x;
  const int tx = t&15, ty = t>>4;
  if (blk < 64){
    const float* src; unsigned short* dst; int sr0, sc0, sstr;
    if (blk < 16){ src=Wq; dst=WqT; sstr=256; sr0=(blk>>2)*64; sc0=(blk&3)*64; }
    else if (blk < 32){ int b2=blk-16; src=pw; dst=pwT; sstr=256; sr0=(b2>>2)*64; sc0=(b2&3)*64; }
    else { int b2=blk-32; src=Wkv; dst=WkvT; sstr=512; sr0=(b2>>3)*64; sc0=(b2&7)*64; }
#pragma unroll
    for (int j=0;j<4;++j){
      f32x4 v = *(const f32x4*)&src[(size_t)(sr0+ty+j*16)*sstr + sc0 + tx*4];
      tile[ty+j*16][tx*4+0]=v[0]; tile[ty+j*16][tx*4+1]=v[1];
      tile[ty+j*16][tx*4+2]=v[2]; tile[ty+j*16][tx*4+3]=v[3];
    }
    __syncthreads();
    const int nr = t>>2, ccb = (t&3)*16;
    u16x8 o0, o1;
#pragma unroll
    for (int u=0;u<8;++u){ o0[u]=f2b(tile[ccb+u][nr]); o1[u]=f2b(tile[ccb+8+u][nr]); }
    unsigned short* dp = &dst[(size_t)(sc0+nr)*256 + sr0 + ccb];
    *(u16x8*)dp = o0;
    *(u16x8*)(dp+8) = o1;
  } else if (blk < 1088){
    int j = (blk-64)*256 + t;
    int o=j>>10, rem=j&1023, khw=rem>>8, ci=rem&255;
    srwb2[j] = f2b(srw[o*1024 + ci*4 + khw]);
  } else if (blk < 1216){
    int i = (blk-1088)*256 + t;
    if (i < 16384){
      int bh=i>>9, r=i&511, ridx=r>>5, d=r&31;
      int row = 776 + (ridx&7) + (ridx>>3)*16;
      kb[((size_t)bh*NKVP + row)*HD + d] = 0;
    } else {
      int j=i-16384;
      int bh=j>>9, r=j&511, d=r>>4, key=784+(r&15);
      vT[((size_t)bh*HD + d)*NKVP + key] = 0;
    }
  } else if (blk < 4352){
    int n = blk - 1216;
    if (t < 200){
      int nr2 = (n*9363)>>19, nc = n - nr2*56;
      u16x4 o;
#pragma unroll
      for (int j=0;j<4;++j){
        int key = t*4 + j;
        float v;
        if (key < NKV){
          int tt = (key*9363)>>19, mm = key - tt*56;
          v = pos[(tt-nr2+55)*PEW + (mm-nc+55)] * LOG2E;
        } else v = -100000.f;
        o[j] = f2b(v);
      }
      *(u16x4*)&bias2[(size_t)n*NKVP + t*4] = o;
    }
  } else {
    int bx = blk - 4352;
    const int n0 = (bx%49)*64; int c4 = bx/49;
    const int c0 = (c4&3)*64, b = c4>>2;
#pragma unroll
    for (int j=0;j<4;++j){
      f32x4 v = *(const f32x4*)&x[(size_t)(b*CD + c0+ty+j*16)*NTOK + n0 + tx*4];
      tile[ty+j*16][tx*4+0]=v[0]; tile[ty+j*16][tx*4+1]=v[1];
      tile[ty+j*16][tx*4+2]=v[2]; tile[ty+j*16][tx*4+3]=v[3];
    }
    __syncthreads();
    const int nr = t>>2, ccb = (t&3)*16;
    u16x8 o0, o1;
#pragma unroll
    for (int u=0;u<8;++u){ o0[u]=f2b(tile[ccb+u][nr]); o1[u]=f2b(tile[ccb+8+u][nr]); }
    unsigned short* dst = &xbf[((size_t)b*NTOK + n0+nr)*CD + c0 + ccb];
    *(u16x8*)dst = o0;
    *(u16x8*)(dst+8) = o1;
  }
}

// ---- fused qproj (blocks 0..783) + conv (784..979), 2-deep pipelines
__global__ __launch_bounds__(256) void k_qc(const unsigned short* __restrict__ xbf,
      const unsigned short* __restrict__ WqT, const unsigned short* __restrict__ srwb2,
      const float* __restrict__ srb, unsigned short* __restrict__ qb,
      float* __restrict__ convo){
  const int gid = blockIdx.x;
  const int tid=threadIdx.x, wv=tid>>6, l=tid&63, g=l>>4, ln16=l&15;
  if (gid < 784){
    const int bx = gid % 196, by = gid / 196;
    const int bI = bx/49;
    const int n0 = (bx%49)*64;
    const int m0 = n0 + (wv>>1)*32;
    const int c0 = by*64 + (wv&1)*32;
    const unsigned short* ap0 = &xbf[((size_t)bI*NTOK + m0+ln16)*CD + g*8];
    const unsigned short* ap1 = ap0 + 16*CD;
    const unsigned short* bp0 = &WqT[(size_t)(c0+ln16)*CD + g*8];
    const unsigned short* bp1 = bp0 + 16*CD;
    f32x4 acc[2][2] = {};
    s16x8 ra0[3], ra1[3], rw0[3], rw1[3];
    ra0[0]=*(const s16x8*)ap0; ra1[0]=*(const s16x8*)ap1;
    rw0[0]=*(const s16x8*)bp0; rw1[0]=*(const s16x8*)bp1;
    ra0[1]=*(const s16x8*)(ap0+32); ra1[1]=*(const s16x8*)(ap1+32);
    rw0[1]=*(const s16x8*)(bp0+32); rw1[1]=*(const s16x8*)(bp1+32);
#pragma unroll
    for (int i=0;i<8;++i){
      if (i<6){
        ra0[(i+2)%3]=*(const s16x8*)(ap0+(i+2)*32);
        ra1[(i+2)%3]=*(const s16x8*)(ap1+(i+2)*32);
        rw0[(i+2)%3]=*(const s16x8*)(bp0+(i+2)*32);
        rw1[(i+2)%3]=*(const s16x8*)(bp1+(i+2)*32);
      }
      const int c = i%3;
      acc[0][0] = MFMA16(ra0[c], rw0[c], acc[0][0]);
      acc[0][1] = MFMA16(ra0[c], rw1[c], acc[0][1]);
      acc[1][0] = MFMA16(ra1[c], rw0[c], acc[1][0]);
      acc[1][1] = MFMA16(ra1[c], rw1[c], acc[1][1]);
    }
#pragma unroll
    for (int mi=0;mi<2;++mi)
#pragma unroll
      for (int ni=0;ni<2;++ni){
        int c = c0 + ni*16 + ln16;
#pragma unroll
        for (int r=0;r<4;++r){
          int n = m0 + mi*16 + g*4 + r;
          qb[((size_t)bI*NTOK + n)*CD + c] = f2b(acc[mi][ni][r] * SC2);
        }
      }
  } else {
    const int cid = gid - 784;
    const int m0 = (cid%49)*64 + (wv>>1)*32;
    const int c0 = (cid/49)*64 + (wv&1)*32;
    size_t abase[2][4];
#pragma unroll
    for (int mi=0;mi<2;++mi){
      int m = m0 + mi*16 + ln16;
      int bb = (m>=2352)?3:(m>=1568)?2:(m>=784)?1:0;
      int nk = m - bb*784;
      int pp = (nk*9363)>>18, qq = nk - pp*28;
#pragma unroll
      for (int khw=0;khw<4;++khw){
        int kh = khw>>1, kw = khw&1;
        abase[mi][khw] = ((size_t)bb*NTOK + (2*pp+kh)*56 + 2*qq+kw)*CD;
      }
    }
    const unsigned short* wp0 = &srwb2[(size_t)(c0+ln16)*1024 + g*8];
    const unsigned short* wp1 = wp0 + 16*1024;
    f32x4 acc[2][2] = {};
    s16x8 ra0[3], ra1[3], rw0[3], rw1[3];
    ra0[0]=*(const s16x8*)&xbf[abase[0][0] + g*8];
    ra1[0]=*(const s16x8*)&xbf[abase[1][0] + g*8];
    rw0[0]=*(const s16x8*)wp0; rw1[0]=*(const s16x8*)wp1;
    ra0[1]=*(const s16x8*)&xbf[abase[0][0] + 32 + g*8];
    ra1[1]=*(const s16x8*)&xbf[abase[1][0] + 32 + g*8];
    rw0[1]=*(const s16x8*)(wp0+32); rw1[1]=*(const s16x8*)(wp1+32);
#pragma unroll
    for (int s=0; s<32; ++s){
      if (s<30){
        const int s2 = s+2;
        const int khw2 = (s2>>3)&3, kc2 = (s2&7)*32;
        const int woff = s2*32;
        ra0[s2%3]=*(const s16x8*)&xbf[abase[0][khw2] + kc2 + g*8];
        ra1[s2%3]=*(const s16x8*)&xbf[abase[1][khw2] + kc2 + g*8];
        rw0[s2%3]=*(const s16x8*)(wp0 + woff);
        rw1[s2%3]=*(const s16x8*)(wp1 + woff);
      }
      const int c = s%3;
      acc[0][0] = MFMA16(ra0[c], rw0[c], acc[0][0]);
      acc[0][1] = MFMA16(ra0[c], rw1[c], acc[0][1]);
      acc[1][0] = MFMA16(ra1[c], rw0[c], acc[1][0]);
      acc[1][1] = MFMA16(ra1[c], rw1[c], acc[1][1]);
    }
#pragma unroll
    for (int mi=0;mi<2;++mi)
#pragma unroll
      for (int ni=0;ni<2;++ni){
        int c = c0 + ni*16 + ln16;
        float bias = srb[c];
#pragma unroll
        for (int r=0;r<4;++r){
          int m = m0 + mi*16 + g*4 + r;
          convo[(size_t)m*CD + c] = acc[mi][ni][r] + bias;
        }
      }
  }
}

// ---- fused LayerNorm + kv projection + scatter. grid (49,8); B-side 2-deep
__global__ __launch_bounds__(256) void k_kvln(const float* __restrict__ co,
      const float* __restrict__ gam, const float* __restrict__ bet,
      const unsigned short* __restrict__ WkvT, unsigned short* __restrict__ kb,
      unsigned short* __restrict__ vT){
  __shared__ unsigned short As[64*256];
  const int tid=threadIdx.x, wv=tid>>6, l=tid&63, g=l>>4, ln16=l&15;
  const int m0blk = blockIdx.x*64;
  {
    const int rl = tid>>2, cs = (tid&3)*64;
    const float* src = &co[(size_t)(m0blk+rl)*CD + cs];
    f32x4 vals[16];
    float s=0.f, s2=0.f;
#pragma unroll
    for (int i=0;i<16;++i){
      vals[i] = *(const f32x4*)(src + i*4);
#pragma unroll
      for (int q=0;q<4;++q){ s += vals[i][q]; s2 += vals[i][q]*vals[i][q]; }
    }
    s += __shfl_xor(s,1); s2 += __shfl_xor(s2,1);
    s += __shfl_xor(s,2); s2 += __shfl_xor(s2,2);
    float mu = s*(1.f/CD);
    float rs = rsqrtf(s2*(1.f/CD) - mu*mu + 1e-5f);
#pragma unroll
    for (int u=0;u<8;++u){
      f32x4 g4a = *(const f32x4*)&gam[cs+u*8];
      f32x4 g4b = *(const f32x4*)&gam[cs+u*8+4];
      f32x4 b4a = *(const f32x4*)&bet[cs+u*8];
      f32x4 b4b = *(const f32x4*)&bet[cs+u*8+4];
      u16x8 o;
#pragma unroll
      for (int q=0;q<4;++q){
        o[q]   = f2b((vals[u*2][q]  -mu)*rs*g4a[q] + b4a[q]);
        o[4+q] = f2b((vals[u*2+1][q]-mu)*rs*g4b[q] + b4b[q]);
      }
      int off = (rl*256 + cs + u*8) ^ ((rl&7)<<3);
      *(u16x8*)&As[off] = o;
    }
  }
  __syncthreads();
  const int mw0 = (wv>>1)*32;
  const int c0 = blockIdx.y*64 + (wv&1)*32;
  const unsigned short* bp0 = &WkvT[(size_t)(c0+ln16)*CD + g*8];
  const unsigned short* bp1 = bp0 + 16*CD;
  f32x4 acc[2][2] = {};
  s16x8 rw0[3], rw1[3];
  rw0[0]=*(const s16x8*)bp0; rw1[0]=*(const s16x8*)bp1;
  rw0[1]=*(const s16x8*)(bp0+32); rw1[1]=*(const s16x8*)(bp1+32);
  const int mr0 = mw0 + ln16, mr1 = mw0 + 16 + ln16;
#pragma unroll
  for (int i=0;i<8;++i){
    if (i<6){
      rw0[(i+2)%3]=*(const s16x8*)(bp0+(i+2)*32);
      rw1[(i+2)%3]=*(const s16x8*)(bp1+(i+2)*32);
    }
    const int k0 = i*32;
    s16x8 a0 = *(const s16x8*)&As[(mr0*256 + k0 + g*8) ^ ((mr0&7)<<3)];
    s16x8 a1 = *(const s16x8*)&As[(mr1*256 + k0 + g*8) ^ ((mr1&7)<<3)];
    const int c = i%3;
    acc[0][0] = MFMA16(a0, rw0[c], acc[0][0]);
    acc[0][1] = MFMA16(a0, rw1[c], acc[0][1]);
    acc[1][0] = MFMA16(a1, rw0[c], acc[1][0]);
    acc[1][1] = MFMA16(a1, rw1[c], acc[1][1]);
  }
#pragma unroll
  for (int mi=0;mi<2;++mi)
#pragma unroll
    for (int ni=0;ni<2;++ni){
      int c2 = c0 + ni*16 + ln16;
      int d = c2>>4, hh = (c2>>1)&7;
#pragma unroll
      for (int r=0;r<4;++r){
        int m = m0blk + mw0 + mi*16 + g*4 + r;
        int bq = (m>=2352)?3:(m>=1568)?2:(m>=784)?1:0;
        int nk = m - bq*784;
        unsigned short val = f2b(acc[mi][ni][r]);
        if (c2&1){
          vT[(((size_t)bq*NH+hh)*HD + d)*NKVP + nk] = val;
        } else {
          int chunk = nk & ~31, pos = nk & 31;
          int gg = pos>>3, jj = pos&7;
          int row = (jj<4) ? (gg*4+jj) : (16 + gg*4 + (jj-4));
          kb[(((size_t)bq*NH+hh)*NKVP + chunk + row)*HD + d] = val;
        }
      }
    }
}

// ---- fused attention: BARRIER-FREE wave-private LDS double-buffer, counted vmcnt.
// grid (32, 49) = (bh, ntile); 16 q-rows/wave; bh pins to XCD bh%8.
__global__ __launch_bounds__(256) void k_attn(const unsigned short* __restrict__ qb,
      const unsigned short* __restrict__ kb, const unsigned short* __restrict__ vT,
      const unsigned short* __restrict__ bias2, unsigned short* __restrict__ aout){
  __shared__ unsigned short kvb[4][2][2048];   // [wave][buf][K 1024 | V 1024]
  const int tid=threadIdx.x, wv=tid>>6, l=tid&63, g=l>>4, ln16=l&15;
  const int bh = blockIdx.x, b = bh>>3, h = bh&7;
  const int nw = blockIdx.y*64 + wv*16;
  const s16x8 qf = *(const s16x8*)&qb[((size_t)b*NTOK + nw + ln16)*CD + h*HD + g*8];
  const int r4 = l>>2;
  const int sg = ((l&3) ^ ((r4>>1)&3))*8;     // write-side slot swizzle (global src)
  const unsigned short* kp = kb + (size_t)bh*NKVP*HD + (size_t)r4*HD + sg;
  const unsigned short* vp = vT + (size_t)bh*HD*NKVP + (size_t)r4*NKVP + sg;
  const unsigned short* bp = bias2 + (size_t)(nw + ln16)*NKVP + g*8;
  unsigned short* my0 = &kvb[wv][0][0];
  unsigned short* my1 = &kvb[wv][1][0];
  const int ko0 = ln16*32 + (g ^ ((ln16>>1)&3))*8;   // read-side swizzle
  f32x4 accO0 = {}, accO1 = {};
  float S = 0.f;
  const f32x4 zf = {};
  // prologue: stage chunk 0 into buf0 (K rows 0-15, 16-31; V hd 0-15, 16-31)
  gload16(kp,        my0);
  gload16(kp+512,    my0+512);
  gload16(vp,        my0+1024);
  gload16(vp+16*NKVP, my0+1536);
  u16x8 bb = *(const u16x8*)bp;
  kp += 1024; vp += 32; bp += 32;
#pragma unroll 2
  for (int it=0; it<25; ++it){
    unsigned short* cur = (it&1) ? my1 : my0;
    unsigned short* nxt = (it&1) ? my0 : my1;
    u16x8 nbb = bb;
    if (it < 24){
      gload16(kp,         nxt);
      gload16(kp+512,     nxt+512);
      gload16(vp,         nxt+1024);
      gload16(vp+16*NKVP, nxt+1536);
      nbb = *(const u16x8*)bp;
      kp += 1024; vp += 32; bp += 32;
      asm volatile("s_waitcnt vmcnt(5)" ::: "memory");   // drain chunk(it)+bias(it)
    } else {
      asm volatile("s_waitcnt vmcnt(0)" ::: "memory");
    }
    s16x8 ka0 = *(const s16x8*)&cur[ko0];
    s16x8 ka1 = *(const s16x8*)&cur[512 + ko0];
    s16x8 v0  = *(const s16x8*)&cur[1024 + ko0];
    s16x8 v1  = *(const s16x8*)&cur[1536 + ko0];
    __builtin_amdgcn_s_setprio(1);
    f32x4 d0 = MFMA16(ka0, qf, zf);
    f32x4 d1 = MFMA16(ka1, qf, zf);
    float p[8];
#pragma unroll
    for (int r=0;r<4;++r){
      p[r]   = exp2f(d0[r] + b2f(bb[r]));
      p[4+r] = exp2f(d1[r] + b2f(bb[4+r]));
    }
    S += ((p[0]+p[1])+(p[2]+p[3])) + ((p[4]+p[5])+(p[6]+p[7]));
    s16x8 pf = pack8(p);
    accO0 = MFMA16(pf, v0, accO0);
    accO1 = MFMA16(pf, v1, accO1);
    __builtin_amdgcn_s_setprio(0);
    bb = nbb;
  }
  S += __shfl_xor(S, 16);
  S += __shfl_xor(S, 32);
#pragma unroll
  for (int r=0;r<4;++r){
    float Sr = __shfl(S, g*4 + r);
    float inv = 1.f / Sr;
    int n = nw + g*4 + r;
    aout[((size_t)b*NTOK + n)*CD + h*HD + ln16]      = f2b(accO0[r]*inv);
    aout[((size_t)b*NTOK + n)*CD + h*HD + 16 + ln16] = f2b(accO1[r]*inv);
  }
}

// ---- out projection, 2-deep pipeline. grid (196,4)
__global__ __launch_bounds__(256) void k_proj(const unsigned short* __restrict__ ain,
      const unsigned short* __restrict__ pwT, const float* __restrict__ pb,
      float* __restrict__ out){
  const int tid=threadIdx.x, wv=tid>>6, l=tid&63, g=l>>4, ln16=l&15;
  const int bI = blockIdx.x/49;
  const int n0 = (blockIdx.x%49)*64;
  const int nsub = n0 + (wv&1)*32;
  const int c0 = blockIdx.y*64 + (wv>>1)*32;
  const unsigned short* ap0 = &pwT[(size_t)(c0+ln16)*CD + g*8];
  const unsigned short* ap1 = ap0 + 16*CD;
  const unsigned short* bp0 = &ain[((size_t)bI*NTOK + nsub+ln16)*CD + g*8];
  const unsigned short* bp1 = bp0 + 16*CD;
  f32x4 acc[2][2] = {};
  s16x8 ra0[3], ra1[3], rw0[3], rw1[3];
  ra0[0]=*(const s16x8*)ap0; ra1[0]=*(const s16x8*)ap1;
  rw0[0]=*(const s16x8*)bp0; rw1[0]=*(const s16x8*)bp1;
  ra0[1]=*(const s16x8*)(ap0+32); ra1[1]=*(const s16x8*)(ap1+32);
  rw0[1]=*(const s16x8*)(bp0+32); rw1[1]=*(const s16x8*)(bp1+32);
#pragma unroll
  for (int i=0;i<8;++i){
    if (i<6){
      ra0[(i+2)%3]=*(const s16x8*)(ap0+(i+2)*32);
      ra1[(i+2)%3]=*(const s16x8*)(ap1+(i+2)*32);
      rw0[(i+2)%3]=*(const s16x8*)(bp0+(i+2)*32);
      rw1[(i+2)%3]=*(const s16x8*)(bp1+(i+2)*32);
    }
    const int c = i%3;
    acc[0][0] = MFMA16(ra0[c], rw0[c], acc[0][0]);
    acc[0][1] = MFMA16(ra0[c], rw1[c], acc[0][1]);
    acc[1][0] = MFMA16(ra1[c], rw0[c], acc[1][0]);
    acc[1][1] = MFMA16(ra1[c], rw1[c], acc[1][1]);
  }
#pragma unroll
  for (int mi=0;mi<2;++mi)
#pragma unroll
    for (int r=0;r<4;++r){
      int c = c0 + mi*16 + g*4 + r;
      float bias = pb[c];
#pragma unroll
      for (int ni=0;ni<2;++ni){
        int n = nsub + ni*16 + ln16;
        out[((size_t)bI*CD + c)*NTOK + n] = acc[mi][ni][r] + bias;
      }
    }
}

extern "C" void kernel_launch(void* const* d_in, const int* in_sizes, int n_in,
                              void* d_out, int out_size, void* d_ws, size_t ws_size,
                              hipStream_t stream){
  const float* x   = (const float*)d_in[0];
  const float* Wq  = (const float*)d_in[1];
  const float* Wkv = (const float*)d_in[2];
  const float* srw = (const float*)d_in[3];
  const float* srb = (const float*)d_in[4];
  const float* lng = (const float*)d_in[5];
  const float* lnb = (const float*)d_in[6];
  const float* pos = (const float*)d_in[7];
  const float* pw  = (const float*)d_in[8];
  const float* pb  = (const float*)d_in[9];
  float* out = (float*)d_out;

  unsigned char* p = (unsigned char*)d_ws;
  unsigned short* WqT   = (unsigned short*)(p + 0);
  unsigned short* WkvT  = (unsigned short*)(p + 131072);
  unsigned short* pwT   = (unsigned short*)(p + 393216);
  unsigned short* srwb2 = (unsigned short*)(p + 524288);
  unsigned short* bias2 = (unsigned short*)(p + 1048576);
  unsigned short* xbf   = (unsigned short*)(p + 6066176);
  unsigned short* qbuf  = (unsigned short*)(p + 12488704);
  float*          convo = (float*)        (p + 18911232);
  unsigned short* kbuf  = (unsigned short*)(p + 22122496);
  unsigned short* vT    = (unsigned short*)(p + 23760896);
  unsigned short* aout  = (unsigned short*)(p + 25399296);

  k_prep <<<5136, 256, 0, stream>>>(Wq, Wkv, pw, srw, pos, x,
                                    WqT, WkvT, pwT, srwb2, bias2, xbf, kbuf, vT);
  k_qc   <<<980, 256, 0, stream>>>(xbf, WqT, srwb2, srb, qbuf, convo);
  k_kvln <<<dim3(49,8), 256, 0, stream>>>(convo, lng, lnb, WkvT, kbuf, vT);
  k_attn <<<dim3(32,49), 256, 0, stream>>>(qbuf, kbuf, vT, bias2, aout);
  k_proj <<<dim3(196,4), 256, 0, stream>>>(aout, pwT, pb, out);
}